// Round 5
// baseline (339.917 us; speedup 1.0000x reference)
//
#include <hip/hip_runtime.h>
#include <hip/hip_bf16.h>

typedef __attribute__((ext_vector_type(8))) short short8;   // 8 bf16 = MFMA A/B frag
typedef __attribute__((ext_vector_type(4))) short short4v;  // 4 bf16
typedef __attribute__((ext_vector_type(4))) float f32x4;    // MFMA C/D

#define MFMA16(A,B,C) __builtin_amdgcn_mfma_f32_16x16x32_bf16((A),(B),(C),0,0,0)

static __device__ __forceinline__ unsigned short f2bf(float f) {
  unsigned int u = __float_as_uint(f);
  unsigned int rnd = 0x7fffu + ((u >> 16) & 1u);   // round-to-nearest-even
  return (unsigned short)((u + rnd) >> 16);
}

// ---------------- prep: bf16 weights, pre-scaled/padded q, padded bias ----------------
__global__ void prep_kernel(const float* __restrict__ qg,
                            const float* __restrict__ wqkv,
                            const float* __restrict__ wproj,
                            const float* __restrict__ btab,
                            unsigned short* __restrict__ wq_bf,   // [384][192]
                            unsigned short* __restrict__ wp_bf,   // [192][192]
                            unsigned short* __restrict__ q_bf,    // [32][6][64][32]
                            float* __restrict__ bias_t)           // [6][64][64]
{
  const int t = blockIdx.x * 256 + threadIdx.x;
  if (t < 32*6*64*32) {
    const int d = t & 31, n = (t >> 5) & 63;
    const int bh = t >> 11;            // b*6 + h
    const int h = bh % 6, b = bh / 6;
    float v = 0.f;
    if (n < 49) v = qg[((b * 6 + h) * 49 + n) * 32 + d] * 0.17677669529663687f; // *D^-0.5
    q_bf[t] = f2bf(v);
  }
  if (t < 384*192) wq_bf[t] = f2bf(wqkv[t]);
  if (t < 192*192) wp_bf[t] = f2bf(wproj[t]);
  if (t < 6*64*64) {
    const int m = t & 63, n = (t >> 6) & 63, h = t >> 12;
    float v;
    if (m >= 49) v = -1e30f;           // mask padded keys (exp -> 0, no max needed)
    else if (n >= 49) v = 0.f;         // padded query rows: anything finite
    else {
      const int ci = n / 7, cj = n % 7, mi = m / 7, mj = m % 7;
      const int idx = (ci - mi + 6) * 13 + (cj - mj + 6);
      v = btab[idx * 6 + h];
    }
    bias_t[t] = v;
  }
}

// ---------------- kernel A: KV projection ----------------
// k_g  [w][h][64][32] bf16 (rows n>=49 hold bq -> masked by bias later)
// vT_g [w][h][32][64] bf16 (cols n>=49 hold bq -> multiplied by P=0 later)
__global__ __launch_bounds__(512, 8)
void kv_proj(const float* __restrict__ x,
             const float* __restrict__ b_qkv,
             const unsigned short* __restrict__ wq_bf,
             unsigned short* __restrict__ k_g,
             unsigned short* __restrict__ vT_g)
{
  __shared__ unsigned short x_lds[64 * 200];   // 25600 B -> 4 blocks/CU (wave-slot cap)
  const f32x4 ZERO4 = {0.f, 0.f, 0.f, 0.f};
  const int tid = threadIdx.x;
  const int wv = tid >> 6;
  const int l  = tid & 63;
  const int lr = l & 15;
  const int lq = l >> 4;
  const int w  = blockIdx.x;

  // stage 1: x -> LDS bf16, zero-pad rows 49..63
  {
    const float* xw = x + (size_t)w * (49 * 192);
    for (int i = tid; i < 2352; i += 512) {
      const float4 v = *reinterpret_cast<const float4*>(xw + i * 4);
      const int e = i * 4;
      const int row = e / 192, col = e % 192;
      short4v pk;
      pk[0] = (short)f2bf(v.x); pk[1] = (short)f2bf(v.y);
      pk[2] = (short)f2bf(v.z); pk[3] = (short)f2bf(v.w);
      *reinterpret_cast<short4v*>(&x_lds[row * 200 + col]) = pk;
    }
    for (int i = tid; i < 720; i += 512) {
      const int e = i * 4;
      const int row = 49 + e / 192, col = e % 192;
      short4v z = {0, 0, 0, 0};
      *reinterpret_cast<short4v*>(&x_lds[row * 200 + col]) = z;
    }
  }
  __syncthreads();

  // stage 2: kv = x @ w_qkv^T + b_qkv -> global K / V^T (bf16)
  {
    short8 afr[4][6];
#pragma unroll
    for (int mt = 0; mt < 4; ++mt)
#pragma unroll
      for (int kb = 0; kb < 6; ++kb)
        afr[mt][kb] = *reinterpret_cast<const short8*>(
            &x_lds[(mt * 16 + lr) * 200 + kb * 32 + lq * 8]);

    for (int ct = 0; ct < 3; ++ct) {
      const int j = wv * 48 + ct * 16 + lr;   // 0..383
      short8 bfr[6];
#pragma unroll
      for (int kb = 0; kb < 6; ++kb)
        bfr[kb] = *reinterpret_cast<const short8*>(&wq_bf[j * 192 + kb * 32 + lq * 8]);
      const float bq = b_qkv[j];
      f32x4 acc[4];
#pragma unroll
      for (int mt = 0; mt < 4; ++mt) acc[mt] = ZERO4;
#pragma unroll
      for (int kb = 0; kb < 6; ++kb)
#pragma unroll
        for (int mt = 0; mt < 4; ++mt)
          acc[mt] = MFMA16(afr[mt][kb], bfr[kb], acc[mt]);

      if (j < 192) {                  // K: k_g[w][h][n][d]
        const int h = j >> 5, d = j & 31;
        unsigned short* kp = k_g + (size_t)(w * 6 + h) * 2048 + d;
#pragma unroll
        for (int mt = 0; mt < 4; ++mt) {
          const int n0 = mt * 16 + lq * 4;
#pragma unroll
          for (int r = 0; r < 4; ++r)
            kp[(n0 + r) * 32] = f2bf(acc[mt][r] + bq);
        }
      } else {                        // V: vT_g[w][h][d][n], packed 4-elem stores
        const int jj = j - 192, h = jj >> 5, d = jj & 31;
        unsigned short* vp = vT_g + (size_t)(w * 6 + h) * 2048 + d * 64;
#pragma unroll
        for (int mt = 0; mt < 4; ++mt) {
          const int n0 = mt * 16 + lq * 4;
          short4v pk;
#pragma unroll
          for (int r = 0; r < 4; ++r) pk[r] = (short)f2bf(acc[mt][r] + bq);
          *reinterpret_cast<short4v*>(&vp[n0]) = pk;
        }
      }
    }
  }
}

// ---------------- kernel B: attention + output projection ----------------
// LDS: p_all 8*1152*2 = 18432 B (per-wave P scratch), o_lds 25600 B -> 44032 B -> 3 blocks/CU
__global__ __launch_bounds__(512, 6)
void attn_proj(const float* __restrict__ b_proj,
               const unsigned short* __restrict__ wp_bf,
               const unsigned short* __restrict__ q_bf,
               const float* __restrict__ bias_t,
               const unsigned short* __restrict__ k_g,
               const unsigned short* __restrict__ vT_g,
               float* __restrict__ out)
{
  __shared__ unsigned short p_all[8 * 1152];
  __shared__ unsigned short o_lds[64 * 200];
  const f32x4 ZERO4 = {0.f, 0.f, 0.f, 0.f};
  const int tid = threadIdx.x;
  const int wv = tid >> 6;
  const int l  = tid & 63;
  const int lr = l & 15;
  const int lq = l >> 4;
  const int w  = blockIdx.x;
  unsigned short* p_lds = p_all + wv * 1152;   // per-wave [16][72]
  const int nt = wv & 3;
  const int ch = wv >> 2;
  const int img = w >> 6;                       // 64 windows per image

#pragma unroll
  for (int rd = 0; rd < 3; ++rd) {
    const int h = ch + 2 * rd;
    const size_t whb = (size_t)(w * 6 + h) * 2048;
    const short8 aq = *reinterpret_cast<const short8*>(
        &q_bf[((img * 6 + h) * 64 + nt * 16 + lr) * 32 + lq * 8]);
    f32x4 s[4];
#pragma unroll
    for (int mt = 0; mt < 4; ++mt) {
      const short8 bk = *reinterpret_cast<const short8*>(
          &k_g[whb + (mt * 16 + lr) * 32 + lq * 8]);
      s[mt] = MFMA16(bk, aq, ZERO4);            // D = S^T
    }
    // bias + exp in-lane; P^T packed to per-wave LDS
    const float* bb4 = bias_t + h * 4096 + (nt * 16 + lr) * 64 + lq * 4;
    float lsum = 0.f;
#pragma unroll
    for (int mt = 0; mt < 4; ++mt) {
      const float4 b4 = *reinterpret_cast<const float4*>(bb4 + mt * 16);
      const float p0 = __expf(s[mt][0] + b4.x);
      const float p1 = __expf(s[mt][1] + b4.y);
      const float p2 = __expf(s[mt][2] + b4.z);
      const float p3 = __expf(s[mt][3] + b4.w);
      lsum += (p0 + p1) + (p2 + p3);
      short4v pk;
      pk[0] = (short)f2bf(p0); pk[1] = (short)f2bf(p1);
      pk[2] = (short)f2bf(p2); pk[3] = (short)f2bf(p3);
      *reinterpret_cast<short4v*>(&p_lds[lr * 72 + mt * 16 + lq * 4]) = pk;
    }
    lsum += __shfl_xor(lsum, 16, 64);
    lsum += __shfl_xor(lsum, 32, 64);
    const float rs = 1.0f / lsum;
    float rinv[4];
#pragma unroll
    for (int r = 0; r < 4; ++r)
      rinv[r] = __shfl(rs, lq * 4 + r, 16);
    // PV: O[16 x 32] = P[16 x 64] * V[64 x 32]; V^T frags straight from global
    f32x4 o0 = ZERO4, o1 = ZERO4;
#pragma unroll
    for (int kb = 0; kb < 2; ++kb) {
      const short8 pa = *reinterpret_cast<const short8*>(&p_lds[lr * 72 + kb * 32 + lq * 8]);
      const short8 bv0 = *reinterpret_cast<const short8*>(
          &vT_g[whb + lr * 64 + kb * 32 + lq * 8]);
      const short8 bv1 = *reinterpret_cast<const short8*>(
          &vT_g[whb + (16 + lr) * 64 + kb * 32 + lq * 8]);
      o0 = MFMA16(pa, bv0, o0);
      o1 = MFMA16(pa, bv1, o1);
    }
#pragma unroll
    for (int r = 0; r < 4; ++r) {
      const int n = nt * 16 + lq * 4 + r;
      o_lds[n * 200 + h * 32 + lr]      = f2bf(o0[r] * rinv[r]);
      o_lds[n * 200 + h * 32 + 16 + lr] = f2bf(o1[r] * rinv[r]);
    }
  }
  __syncthreads();   // single barrier: O complete

  // out = o @ w_proj^T + b_proj
  {
    const int mt = wv & 3;
    const int cc = wv >> 2;
    short8 af[6];
#pragma unroll
    for (int kb = 0; kb < 6; ++kb)
      af[kb] = *reinterpret_cast<const short8*>(&o_lds[(mt * 16 + lr) * 200 + kb * 32 + lq * 8]);
    float* op = out + (size_t)w * 9408;
    for (int ct = 0; ct < 6; ++ct) {
      const int cp = cc * 96 + ct * 16 + lr;
      short8 bf[6];
#pragma unroll
      for (int kb = 0; kb < 6; ++kb)
        bf[kb] = *reinterpret_cast<const short8*>(&wp_bf[cp * 192 + kb * 32 + lq * 8]);
      f32x4 acc = ZERO4;
#pragma unroll
      for (int kb = 0; kb < 6; ++kb) acc = MFMA16(af[kb], bf[kb], acc);
      const float bb = b_proj[cp];
      const int n0 = mt * 16 + lq * 4;
#pragma unroll
      for (int r = 0; r < 4; ++r)
        if (n0 + r < 49) op[(n0 + r) * 192 + cp] = acc[r] + bb;
    }
  }
}

// ---------------- fallback: fused kernel (R4, known-good) for small ws ----------------
__global__ __launch_bounds__(512, 4)
void fused_win_attn(const float* __restrict__ x,
                    const float* __restrict__ b_qkv,
                    const float* __restrict__ b_proj,
                    const unsigned short* __restrict__ wq_bf,
                    const unsigned short* __restrict__ wp_bf,
                    const unsigned short* __restrict__ q_bf,
                    const float* __restrict__ bias_t,
                    float* __restrict__ out)
{
  extern __shared__ unsigned short lds[];
  unsigned short* x_lds  = lds;
  unsigned short* k_lds  = lds + 12800;
  unsigned short* vT_lds = lds + 26624;
  unsigned short* o_lds  = lds + 12800;

  const f32x4 ZERO4 = {0.f, 0.f, 0.f, 0.f};
  const int tid = threadIdx.x;
  const int wv = tid >> 6;
  const int l  = tid & 63;
  const int lr = l & 15;
  const int lq = l >> 4;
  const int w  = blockIdx.x;

  {
    const float* xw = x + (size_t)w * (49 * 192);
    for (int i = tid; i < 2352; i += 512) {
      const float4 v = *reinterpret_cast<const float4*>(xw + i * 4);
      const int e = i * 4;
      const int row = e / 192, col = e % 192;
      short4v pk;
      pk[0] = (short)f2bf(v.x); pk[1] = (short)f2bf(v.y);
      pk[2] = (short)f2bf(v.z); pk[3] = (short)f2bf(v.w);
      *reinterpret_cast<short4v*>(&x_lds[row * 200 + col]) = pk;
    }
    for (int i = tid; i < 720; i += 512) {
      const int e = i * 4;
      const int row = 49 + e / 192, col = e % 192;
      short4v z = {0, 0, 0, 0};
      *reinterpret_cast<short4v*>(&x_lds[row * 200 + col]) = z;
    }
  }
  __syncthreads();

  {
    short8 afr[4][6];
#pragma unroll
    for (int mt = 0; mt < 4; ++mt)
#pragma unroll
      for (int kb = 0; kb < 6; ++kb)
        afr[mt][kb] = *reinterpret_cast<const short8*>(
            &x_lds[(mt * 16 + lr) * 200 + kb * 32 + lq * 8]);

    for (int ct = 0; ct < 3; ++ct) {
      const int j = wv * 48 + ct * 16 + lr;
      short8 bfr[6];
#pragma unroll
      for (int kb = 0; kb < 6; ++kb)
        bfr[kb] = *reinterpret_cast<const short8*>(&wq_bf[j * 192 + kb * 32 + lq * 8]);
      const float bq = b_qkv[j];
      f32x4 acc[4];
#pragma unroll
      for (int mt = 0; mt < 4; ++mt) acc[mt] = ZERO4;
#pragma unroll
      for (int kb = 0; kb < 6; ++kb)
#pragma unroll
        for (int mt = 0; mt < 4; ++mt)
          acc[mt] = MFMA16(afr[mt][kb], bfr[kb], acc[mt]);

      if (j < 192) {
        const int h = j >> 5, d = j & 31;
#pragma unroll
        for (int mt = 0; mt < 4; ++mt) {
          const int n0 = mt * 16 + lq * 4;
#pragma unroll
          for (int r = 0; r < 4; ++r)
            k_lds[h * 2304 + (n0 + r) * 36 + d] = f2bf(acc[mt][r] + bq);
        }
      } else {
        const int jj = j - 192, h = jj >> 5, d = jj & 31;
#pragma unroll
        for (int mt = 0; mt < 4; ++mt) {
          const int n0 = mt * 16 + lq * 4;
          short4v pk;
#pragma unroll
          for (int r = 0; r < 4; ++r) pk[r] = (short)f2bf(acc[mt][r] + bq);
          *reinterpret_cast<short4v*>(&vT_lds[h * 2176 + d * 68 + n0]) = pk;
        }
      }
    }
  }
  __syncthreads();

  unsigned short* p_lds = x_lds + wv * (16 * 72);
  const int nt = wv & 3;
  const int img = w >> 6;
  f32x4 o_reg[3][2];
#pragma unroll
  for (int rd = 0; rd < 3; ++rd) {
    const int h = (wv >> 2) + 2 * rd;
    const short8 aq = *reinterpret_cast<const short8*>(
        &q_bf[((img * 6 + h) * 64 + nt * 16 + lr) * 32 + lq * 8]);
    f32x4 s[4];
#pragma unroll
    for (int mt = 0; mt < 4; ++mt) {
      const unsigned short* kp = &k_lds[h * 2304 + (mt * 16 + lr) * 36 + lq * 8];
      const short4v k0 = *reinterpret_cast<const short4v*>(kp);
      const short4v k1 = *reinterpret_cast<const short4v*>(kp + 4);
      short8 bk;
      bk[0]=k0[0]; bk[1]=k0[1]; bk[2]=k0[2]; bk[3]=k0[3];
      bk[4]=k1[0]; bk[5]=k1[1]; bk[6]=k1[2]; bk[7]=k1[3];
      s[mt] = MFMA16(bk, aq, ZERO4);
    }
    const float* bb4 = bias_t + h * 4096 + (nt * 16 + lr) * 64 + lq * 4;
    float lsum = 0.f;
#pragma unroll
    for (int mt = 0; mt < 4; ++mt) {
      const float4 b4 = *reinterpret_cast<const float4*>(bb4 + mt * 16);
      const float p0 = __expf(s[mt][0] + b4.x);
      const float p1 = __expf(s[mt][1] + b4.y);
      const float p2 = __expf(s[mt][2] + b4.z);
      const float p3 = __expf(s[mt][3] + b4.w);
      lsum += (p0 + p1) + (p2 + p3);
      short4v pk;
      pk[0] = (short)f2bf(p0); pk[1] = (short)f2bf(p1);
      pk[2] = (short)f2bf(p2); pk[3] = (short)f2bf(p3);
      *reinterpret_cast<short4v*>(&p_lds[lr * 72 + mt * 16 + lq * 4]) = pk;
    }
    lsum += __shfl_xor(lsum, 16, 64);
    lsum += __shfl_xor(lsum, 32, 64);
    const float rs = 1.0f / lsum;
    float rinv[4];
#pragma unroll
    for (int r = 0; r < 4; ++r)
      rinv[r] = __shfl(rs, lq * 4 + r, 16);
    f32x4 o0 = ZERO4, o1 = ZERO4;
#pragma unroll
    for (int kb = 0; kb < 2; ++kb) {
      const short8 pa = *reinterpret_cast<const short8*>(&p_lds[lr * 72 + kb * 32 + lq * 8]);
      const unsigned short* vp0 = &vT_lds[h * 2176 + lr * 68 + kb * 32 + lq * 8];
      const unsigned short* vp1 = &vT_lds[h * 2176 + (16 + lr) * 68 + kb * 32 + lq * 8];
      const short4v a0 = *reinterpret_cast<const short4v*>(vp0);
      const short4v a1 = *reinterpret_cast<const short4v*>(vp0 + 4);
      short8 bv0; bv0[0]=a0[0];bv0[1]=a0[1];bv0[2]=a0[2];bv0[3]=a0[3];
                  bv0[4]=a1[0];bv0[5]=a1[1];bv0[6]=a1[2];bv0[7]=a1[3];
      o0 = MFMA16(pa, bv0, o0);
      const short4v c0 = *reinterpret_cast<const short4v*>(vp1);
      const short4v c1 = *reinterpret_cast<const short4v*>(vp1 + 4);
      short8 bv1; bv1[0]=c0[0];bv1[1]=c0[1];bv1[2]=c0[2];bv1[3]=c0[3];
                  bv1[4]=c1[0];bv1[5]=c1[1];bv1[6]=c1[2];bv1[7]=c1[3];
      o1 = MFMA16(pa, bv1, o1);
    }
#pragma unroll
    for (int r = 0; r < 4; ++r) {
      o_reg[rd][0][r] = o0[r] * rinv[r];
      o_reg[rd][1][r] = o1[r] * rinv[r];
    }
  }
  __syncthreads();

#pragma unroll
  for (int rd = 0; rd < 3; ++rd) {
    const int h = (wv >> 2) + 2 * rd;
#pragma unroll
    for (int r = 0; r < 4; ++r) {
      const int n = nt * 16 + lq * 4 + r;
      o_lds[n * 200 + h * 32 + lr]      = f2bf(o_reg[rd][0][r]);
      o_lds[n * 200 + h * 32 + 16 + lr] = f2bf(o_reg[rd][1][r]);
    }
  }
  __syncthreads();

  {
    const int mt = wv & 3;
    const int cc = wv >> 2;
    short8 af[6];
#pragma unroll
    for (int kb = 0; kb < 6; ++kb)
      af[kb] = *reinterpret_cast<const short8*>(&o_lds[(mt * 16 + lr) * 200 + kb * 32 + lq * 8]);
    float* op = out + (size_t)w * 9408;
    for (int ct = 0; ct < 6; ++ct) {
      const int cp = cc * 96 + ct * 16 + lr;
      short8 bf[6];
#pragma unroll
      for (int kb = 0; kb < 6; ++kb)
        bf[kb] = *reinterpret_cast<const short8*>(&wp_bf[cp * 192 + kb * 32 + lq * 8]);
      f32x4 acc = ZERO4;
#pragma unroll
      for (int kb = 0; kb < 6; ++kb) acc = MFMA16(af[kb], bf[kb], acc);
      const float bb = b_proj[cp];
      const int n0 = mt * 16 + lq * 4;
#pragma unroll
      for (int r = 0; r < 4; ++r)
        if (n0 + r < 49) op[(n0 + r) * 192 + cp] = acc[r] + bb;
    }
  }
}

extern "C" void kernel_launch(void* const* d_in, const int* in_sizes, int n_in,
                              void* d_out, int out_size, void* d_ws, size_t ws_size,
                              hipStream_t stream) {
  const float* x     = (const float*)d_in[0];
  const float* qg    = (const float*)d_in[1];
  const float* wqkv  = (const float*)d_in[2];
  const float* bqkv  = (const float*)d_in[3];
  const float* btab  = (const float*)d_in[4];
  const float* wproj = (const float*)d_in[5];
  const float* bproj = (const float*)d_in[6];
  float* out = (float*)d_out;

  char* ws = (char*)d_ws;
  unsigned short* wq_bf = (unsigned short*)(ws);            // 147456 B
  unsigned short* wp_bf = (unsigned short*)(ws + 147456);   //  73728 B
  unsigned short* q_bf  = (unsigned short*)(ws + 221184);   // 786432 B
  float* bias_t         = (float*)(ws + 1007616);           //  98304 B
  unsigned short* k_g   = (unsigned short*)(ws + 1105920);  // 50331648 B
  unsigned short* vT_g  = (unsigned short*)(ws + 51437568); // 50331648 B -> total 101769216 B

  hipLaunchKernelGGL(prep_kernel, dim3(1536), dim3(256), 0, stream,
                     qg, wqkv, wproj, btab, wq_bf, wp_bf, q_bf, bias_t);
  if (ws_size >= 101769216ull) {
    hipLaunchKernelGGL(kv_proj, dim3(2048), dim3(512), 0, stream,
                       x, bqkv, wq_bf, k_g, vT_g);
    hipLaunchKernelGGL(attn_proj, dim3(2048), dim3(512), 0, stream,
                       bproj, wp_bf, q_bf, bias_t, k_g, vT_g, out);
  } else {
    hipLaunchKernelGGL(fused_win_attn, dim3(2048), dim3(512), 79360, stream,
                       x, bqkv, bproj, wq_bf, wp_bf, q_bf, bias_t, out);
  }
}

// Round 6
// 197.998 us; speedup vs baseline: 1.7168x; 1.7168x over previous
//
#include <hip/hip_runtime.h>
#include <hip/hip_bf16.h>

typedef __attribute__((ext_vector_type(8))) short short8;   // 8 bf16 = MFMA A/B frag
typedef __attribute__((ext_vector_type(4))) short short4v;  // 4 bf16
typedef __attribute__((ext_vector_type(4))) float f32x4;    // MFMA C/D

#define MFMA16(A,B,C) __builtin_amdgcn_mfma_f32_16x16x32_bf16((A),(B),(C),0,0,0)

static __device__ __forceinline__ unsigned short f2bf(float f) {
  unsigned int u = __float_as_uint(f);
  unsigned int rnd = 0x7fffu + ((u >> 16) & 1u);   // round-to-nearest-even
  return (unsigned short)((u + rnd) >> 16);
}

// ---------------- prep: bf16 weights, pre-scaled/padded q, padded bias ----------------
__global__ void prep_kernel(const float* __restrict__ qg,
                            const float* __restrict__ wqkv,
                            const float* __restrict__ wproj,
                            const float* __restrict__ btab,
                            unsigned short* __restrict__ wq_bf,   // [384][192]
                            unsigned short* __restrict__ wp_bf,   // [192][192]
                            unsigned short* __restrict__ q_bf,    // [32][6][64][32]
                            float* __restrict__ bias_t)           // [6][64][64]
{
  const int t = blockIdx.x * 256 + threadIdx.x;
  if (t < 32*6*64*32) {
    const int d = t & 31, n = (t >> 5) & 63;
    const int bh = t >> 11;            // b*6 + h
    const int h = bh % 6, b = bh / 6;
    float v = 0.f;
    if (n < 49) v = qg[((b * 6 + h) * 49 + n) * 32 + d] * 0.17677669529663687f; // *D^-0.5
    q_bf[t] = f2bf(v);
  }
  if (t < 384*192) wq_bf[t] = f2bf(wqkv[t]);
  if (t < 192*192) wp_bf[t] = f2bf(wproj[t]);
  if (t < 6*64*64) {
    const int m = t & 63, n = (t >> 6) & 63, h = t >> 12;
    float v;
    if (m >= 49) v = -1e30f;           // mask padded keys (exp -> 0, no max needed)
    else if (n >= 49) v = 0.f;         // padded query rows: anything finite
    else {
      const int ci = n / 7, cj = n % 7, mi = m / 7, mj = m % 7;
      const int idx = (ci - mi + 6) * 13 + (cj - mj + 6);
      v = btab[idx * 6 + h];
    }
    bias_t[t] = v;
  }
}

// ---------------- kernel A: KV projection, LDS-staged coalesced stores ----------------
// kv_g per window (24576 elems): [0,12288) K [6][64][32]; [12288,24576) V^T [6][32][64]
__global__ __launch_bounds__(512, 4)
void kv_proj(const float* __restrict__ x,
             const float* __restrict__ b_qkv,
             const unsigned short* __restrict__ wq_bf,
             unsigned short* __restrict__ kv_g)
{
  __shared__ unsigned short x_lds[64 * 200];     // 25600 B
  __shared__ unsigned short k_lds[6 * 64 * 36];  // 27648 B (pad 36: conflict-light writes)
  __shared__ unsigned short v_lds[6 * 32 * 68];  // 26112 B (pad 68)
  const f32x4 ZERO4 = {0.f, 0.f, 0.f, 0.f};
  const int tid = threadIdx.x;
  const int wv = tid >> 6;
  const int l  = tid & 63;
  const int lr = l & 15;
  const int lq = l >> 4;
  const int w  = blockIdx.x;

  // stage 1: x -> LDS bf16, zero-pad rows 49..63
  {
    const float* xw = x + (size_t)w * (49 * 192);
    for (int i = tid; i < 2352; i += 512) {
      const float4 v = *reinterpret_cast<const float4*>(xw + i * 4);
      const int e = i * 4;
      const int row = e / 192, col = e % 192;
      short4v pk;
      pk[0] = (short)f2bf(v.x); pk[1] = (short)f2bf(v.y);
      pk[2] = (short)f2bf(v.z); pk[3] = (short)f2bf(v.w);
      *reinterpret_cast<short4v*>(&x_lds[row * 200 + col]) = pk;
    }
    for (int i = tid; i < 720; i += 512) {
      const int e = i * 4;
      const int row = 49 + e / 192, col = e % 192;
      short4v z = {0, 0, 0, 0};
      *reinterpret_cast<short4v*>(&x_lds[row * 200 + col]) = z;
    }
  }
  __syncthreads();

  // stage 2: kv = x @ w_qkv^T + b_qkv -> k_lds / v_lds
  {
    short8 afr[4][6];
#pragma unroll
    for (int mt = 0; mt < 4; ++mt)
#pragma unroll
      for (int kb = 0; kb < 6; ++kb)
        afr[mt][kb] = *reinterpret_cast<const short8*>(
            &x_lds[(mt * 16 + lr) * 200 + kb * 32 + lq * 8]);

    for (int ct = 0; ct < 3; ++ct) {
      const int j = wv * 48 + ct * 16 + lr;   // 0..383
      short8 bfr[6];
#pragma unroll
      for (int kb = 0; kb < 6; ++kb)
        bfr[kb] = *reinterpret_cast<const short8*>(&wq_bf[j * 192 + kb * 32 + lq * 8]);
      const float bq = b_qkv[j];
      f32x4 acc[4];
#pragma unroll
      for (int mt = 0; mt < 4; ++mt) acc[mt] = ZERO4;
#pragma unroll
      for (int kb = 0; kb < 6; ++kb)
#pragma unroll
        for (int mt = 0; mt < 4; ++mt)
          acc[mt] = MFMA16(afr[mt][kb], bfr[kb], acc[mt]);

      if (j < 192) {                  // K: k_lds[h][n][36-pad]
        const int h = j >> 5, d = j & 31;
#pragma unroll
        for (int mt = 0; mt < 4; ++mt) {
          const int n0 = mt * 16 + lq * 4;
#pragma unroll
          for (int r = 0; r < 4; ++r)
            k_lds[h * 2304 + (n0 + r) * 36 + d] = f2bf(acc[mt][r] + bq);
        }
      } else {                        // V: v_lds[h][d][68-pad]
        const int jj = j - 192, h = jj >> 5, d = jj & 31;
#pragma unroll
        for (int mt = 0; mt < 4; ++mt) {
          const int n0 = mt * 16 + lq * 4;
          short4v pk;
#pragma unroll
          for (int r = 0; r < 4; ++r) pk[r] = (short)f2bf(acc[mt][r] + bq);
          *reinterpret_cast<short4v*>(&v_lds[h * 2176 + d * 68 + n0]) = pk;
        }
      }
    }
  }
  __syncthreads();

  // copy-out: LDS (padded) -> kv_g (unpadded, linear) with coalesced b64 stores
  {
    unsigned short* dst = kv_g + (size_t)w * 24576;
#pragma unroll
    for (int i = 0; i < 12; ++i) {
      const int e = (i * 512 + tid) * 4;
      short4v vv;
      if (e < 12288) {                // K half: e = h*2048 + n*32 + d
        const int h = e >> 11, n = (e >> 5) & 63, d = e & 31;
        vv = *reinterpret_cast<const short4v*>(&k_lds[h * 2304 + n * 36 + d]);
      } else {                        // V half: e-12288 = h*2048 + d*64 + n
        const int e2 = e - 12288;
        const int h = e2 >> 11, d = (e2 >> 6) & 31, n = e2 & 63;
        vv = *reinterpret_cast<const short4v*>(&v_lds[h * 2176 + d * 68 + n]);
      }
      *reinterpret_cast<short4v*>(&dst[e]) = vv;
    }
  }
}

// ---------------- kernel B: attention + output projection ----------------
// LDS: p_all 18432 B + o_lds 25600 B = 44032 B -> 3 blocks/CU
__global__ __launch_bounds__(512, 6)
void attn_proj(const float* __restrict__ b_proj,
               const unsigned short* __restrict__ wp_bf,
               const unsigned short* __restrict__ q_bf,
               const float* __restrict__ bias_t,
               const unsigned short* __restrict__ kv_g,
               float* __restrict__ out)
{
  __shared__ unsigned short p_all[8 * 1152];
  __shared__ unsigned short o_lds[64 * 200];
  const f32x4 ZERO4 = {0.f, 0.f, 0.f, 0.f};
  const int tid = threadIdx.x;
  const int wv = tid >> 6;
  const int l  = tid & 63;
  const int lr = l & 15;
  const int lq = l >> 4;
  const int w  = blockIdx.x;
  unsigned short* p_lds = p_all + wv * 1152;   // per-wave [16][72]
  const int nt = wv & 3;
  const int ch = wv >> 2;
  const int img = w >> 6;                       // 64 windows per image
  const unsigned short* kvw = kv_g + (size_t)w * 24576;

#pragma unroll
  for (int rd = 0; rd < 3; ++rd) {
    const int h = ch + 2 * rd;
    const unsigned short* kp = kvw + h * 2048;          // K [64][32]
    const unsigned short* vp = kvw + 12288 + h * 2048;  // V^T [32][64]
    // issue ALL global loads for this round up front (K then V); V consumed
    // only after softmax -> latency hidden under QK^T + exp
    short8 kf[4];
#pragma unroll
    for (int mt = 0; mt < 4; ++mt)
      kf[mt] = *reinterpret_cast<const short8*>(&kp[(mt * 16 + lr) * 32 + lq * 8]);
    short8 vf[4];
    vf[0] = *reinterpret_cast<const short8*>(&vp[lr * 64 + lq * 8]);
    vf[1] = *reinterpret_cast<const short8*>(&vp[(16 + lr) * 64 + lq * 8]);
    vf[2] = *reinterpret_cast<const short8*>(&vp[lr * 64 + 32 + lq * 8]);
    vf[3] = *reinterpret_cast<const short8*>(&vp[(16 + lr) * 64 + 32 + lq * 8]);

    const short8 aq = *reinterpret_cast<const short8*>(
        &q_bf[((img * 6 + h) * 64 + nt * 16 + lr) * 32 + lq * 8]);
    f32x4 s[4];
#pragma unroll
    for (int mt = 0; mt < 4; ++mt)
      s[mt] = MFMA16(kf[mt], aq, ZERO4);        // D = S^T
    // bias + exp in-lane; P^T packed to per-wave LDS
    const float* bb4 = bias_t + h * 4096 + (nt * 16 + lr) * 64 + lq * 4;
    float lsum = 0.f;
#pragma unroll
    for (int mt = 0; mt < 4; ++mt) {
      const float4 b4 = *reinterpret_cast<const float4*>(bb4 + mt * 16);
      const float p0 = __expf(s[mt][0] + b4.x);
      const float p1 = __expf(s[mt][1] + b4.y);
      const float p2 = __expf(s[mt][2] + b4.z);
      const float p3 = __expf(s[mt][3] + b4.w);
      lsum += (p0 + p1) + (p2 + p3);
      short4v pk;
      pk[0] = (short)f2bf(p0); pk[1] = (short)f2bf(p1);
      pk[2] = (short)f2bf(p2); pk[3] = (short)f2bf(p3);
      *reinterpret_cast<short4v*>(&p_lds[lr * 72 + mt * 16 + lq * 4]) = pk;
    }
    lsum += __shfl_xor(lsum, 16, 64);
    lsum += __shfl_xor(lsum, 32, 64);
    const float rs = 1.0f / lsum;
    float rinv[4];
#pragma unroll
    for (int r = 0; r < 4; ++r)
      rinv[r] = __shfl(rs, lq * 4 + r, 16);
    // PV: O[16 x 32] = P[16 x 64] * V[64 x 32]
    f32x4 o0 = ZERO4, o1 = ZERO4;
#pragma unroll
    for (int kb = 0; kb < 2; ++kb) {
      const short8 pa = *reinterpret_cast<const short8*>(&p_lds[lr * 72 + kb * 32 + lq * 8]);
      o0 = MFMA16(pa, vf[kb * 2],     o0);
      o1 = MFMA16(pa, vf[kb * 2 + 1], o1);
    }
#pragma unroll
    for (int r = 0; r < 4; ++r) {
      const int n = nt * 16 + lq * 4 + r;
      o_lds[n * 200 + h * 32 + lr]      = f2bf(o0[r] * rinv[r]);
      o_lds[n * 200 + h * 32 + 16 + lr] = f2bf(o1[r] * rinv[r]);
    }
  }
  __syncthreads();   // single barrier: O complete

  // out = o @ w_proj^T + b_proj
  {
    const int mt = wv & 3;
    const int cc = wv >> 2;
    short8 af[6];
#pragma unroll
    for (int kb = 0; kb < 6; ++kb)
      af[kb] = *reinterpret_cast<const short8*>(&o_lds[(mt * 16 + lr) * 200 + kb * 32 + lq * 8]);
    float* op = out + (size_t)w * 9408;
    for (int ct = 0; ct < 6; ++ct) {
      const int cp = cc * 96 + ct * 16 + lr;
      short8 bf[6];
#pragma unroll
      for (int kb = 0; kb < 6; ++kb)
        bf[kb] = *reinterpret_cast<const short8*>(&wp_bf[cp * 192 + kb * 32 + lq * 8]);
      f32x4 acc = ZERO4;
#pragma unroll
      for (int kb = 0; kb < 6; ++kb) acc = MFMA16(af[kb], bf[kb], acc);
      const float bb = b_proj[cp];
      const int n0 = mt * 16 + lq * 4;
#pragma unroll
      for (int r = 0; r < 4; ++r)
        if (n0 + r < 49) op[(n0 + r) * 192 + cp] = acc[r] + bb;
    }
  }
}

// ---------------- fallback: fused kernel (R4, known-good) for small ws ----------------
__global__ __launch_bounds__(512, 4)
void fused_win_attn(const float* __restrict__ x,
                    const float* __restrict__ b_qkv,
                    const float* __restrict__ b_proj,
                    const unsigned short* __restrict__ wq_bf,
                    const unsigned short* __restrict__ wp_bf,
                    const unsigned short* __restrict__ q_bf,
                    const float* __restrict__ bias_t,
                    float* __restrict__ out)
{
  extern __shared__ unsigned short lds[];
  unsigned short* x_lds  = lds;
  unsigned short* k_lds  = lds + 12800;
  unsigned short* vT_lds = lds + 26624;
  unsigned short* o_lds  = lds + 12800;

  const f32x4 ZERO4 = {0.f, 0.f, 0.f, 0.f};
  const int tid = threadIdx.x;
  const int wv = tid >> 6;
  const int l  = tid & 63;
  const int lr = l & 15;
  const int lq = l >> 4;
  const int w  = blockIdx.x;

  {
    const float* xw = x + (size_t)w * (49 * 192);
    for (int i = tid; i < 2352; i += 512) {
      const float4 v = *reinterpret_cast<const float4*>(xw + i * 4);
      const int e = i * 4;
      const int row = e / 192, col = e % 192;
      short4v pk;
      pk[0] = (short)f2bf(v.x); pk[1] = (short)f2bf(v.y);
      pk[2] = (short)f2bf(v.z); pk[3] = (short)f2bf(v.w);
      *reinterpret_cast<short4v*>(&x_lds[row * 200 + col]) = pk;
    }
    for (int i = tid; i < 720; i += 512) {
      const int e = i * 4;
      const int row = 49 + e / 192, col = e % 192;
      short4v z = {0, 0, 0, 0};
      *reinterpret_cast<short4v*>(&x_lds[row * 200 + col]) = z;
    }
  }
  __syncthreads();

  {
    short8 afr[4][6];
#pragma unroll
    for (int mt = 0; mt < 4; ++mt)
#pragma unroll
      for (int kb = 0; kb < 6; ++kb)
        afr[mt][kb] = *reinterpret_cast<const short8*>(
            &x_lds[(mt * 16 + lr) * 200 + kb * 32 + lq * 8]);

    for (int ct = 0; ct < 3; ++ct) {
      const int j = wv * 48 + ct * 16 + lr;
      short8 bfr[6];
#pragma unroll
      for (int kb = 0; kb < 6; ++kb)
        bfr[kb] = *reinterpret_cast<const short8*>(&wq_bf[j * 192 + kb * 32 + lq * 8]);
      const float bq = b_qkv[j];
      f32x4 acc[4];
#pragma unroll
      for (int mt = 0; mt < 4; ++mt) acc[mt] = ZERO4;
#pragma unroll
      for (int kb = 0; kb < 6; ++kb)
#pragma unroll
        for (int mt = 0; mt < 4; ++mt)
          acc[mt] = MFMA16(afr[mt][kb], bfr[kb], acc[mt]);

      if (j < 192) {
        const int h = j >> 5, d = j & 31;
#pragma unroll
        for (int mt = 0; mt < 4; ++mt) {
          const int n0 = mt * 16 + lq * 4;
#pragma unroll
          for (int r = 0; r < 4; ++r)
            k_lds[h * 2304 + (n0 + r) * 36 + d] = f2bf(acc[mt][r] + bq);
        }
      } else {
        const int jj = j - 192, h = jj >> 5, d = jj & 31;
#pragma unroll
        for (int mt = 0; mt < 4; ++mt) {
          const int n0 = mt * 16 + lq * 4;
          short4v pk;
#pragma unroll
          for (int r = 0; r < 4; ++r) pk[r] = (short)f2bf(acc[mt][r] + bq);
          *reinterpret_cast<short4v*>(&vT_lds[h * 2176 + d * 68 + n0]) = pk;
        }
      }
    }
  }
  __syncthreads();

  unsigned short* p_lds = x_lds + wv * (16 * 72);
  const int nt = wv & 3;
  const int img = w >> 6;
  f32x4 o_reg[3][2];
#pragma unroll
  for (int rd = 0; rd < 3; ++rd) {
    const int h = (wv >> 2) + 2 * rd;
    const short8 aq = *reinterpret_cast<const short8*>(
        &q_bf[((img * 6 + h) * 64 + nt * 16 + lr) * 32 + lq * 8]);
    f32x4 s[4];
#pragma unroll
    for (int mt = 0; mt < 4; ++mt) {
      const unsigned short* kp = &k_lds[h * 2304 + (mt * 16 + lr) * 36 + lq * 8];
      const short4v k0 = *reinterpret_cast<const short4v*>(kp);
      const short4v k1 = *reinterpret_cast<const short4v*>(kp + 4);
      short8 bk;
      bk[0]=k0[0]; bk[1]=k0[1]; bk[2]=k0[2]; bk[3]=k0[3];
      bk[4]=k1[0]; bk[5]=k1[1]; bk[6]=k1[2]; bk[7]=k1[3];
      s[mt] = MFMA16(bk, aq, ZERO4);
    }
    const float* bb4 = bias_t + h * 4096 + (nt * 16 + lr) * 64 + lq * 4;
    float lsum = 0.f;
#pragma unroll
    for (int mt = 0; mt < 4; ++mt) {
      const float4 b4 = *reinterpret_cast<const float4*>(bb4 + mt * 16);
      const float p0 = __expf(s[mt][0] + b4.x);
      const float p1 = __expf(s[mt][1] + b4.y);
      const float p2 = __expf(s[mt][2] + b4.z);
      const float p3 = __expf(s[mt][3] + b4.w);
      lsum += (p0 + p1) + (p2 + p3);
      short4v pk;
      pk[0] = (short)f2bf(p0); pk[1] = (short)f2bf(p1);
      pk[2] = (short)f2bf(p2); pk[3] = (short)f2bf(p3);
      *reinterpret_cast<short4v*>(&p_lds[lr * 72 + mt * 16 + lq * 4]) = pk;
    }
    lsum += __shfl_xor(lsum, 16, 64);
    lsum += __shfl_xor(lsum, 32, 64);
    const float rs = 1.0f / lsum;
    float rinv[4];
#pragma unroll
    for (int r = 0; r < 4; ++r)
      rinv[r] = __shfl(rs, lq * 4 + r, 16);
    f32x4 o0 = ZERO4, o1 = ZERO4;
#pragma unroll
    for (int kb = 0; kb < 2; ++kb) {
      const short8 pa = *reinterpret_cast<const short8*>(&p_lds[lr * 72 + kb * 32 + lq * 8]);
      const unsigned short* vp0 = &vT_lds[h * 2176 + lr * 68 + kb * 32 + lq * 8];
      const unsigned short* vp1 = &vT_lds[h * 2176 + (16 + lr) * 68 + kb * 32 + lq * 8];
      const short4v a0 = *reinterpret_cast<const short4v*>(vp0);
      const short4v a1 = *reinterpret_cast<const short4v*>(vp0 + 4);
      short8 bv0; bv0[0]=a0[0];bv0[1]=a0[1];bv0[2]=a0[2];bv0[3]=a0[3];
                  bv0[4]=a1[0];bv0[5]=a1[1];bv0[6]=a1[2];bv0[7]=a1[3];
      o0 = MFMA16(pa, bv0, o0);
      const short4v c0 = *reinterpret_cast<const short4v*>(vp1);
      const short4v c1 = *reinterpret_cast<const short4v*>(vp1 + 4);
      short8 bv1; bv1[0]=c0[0];bv1[1]=c0[1];bv1[2]=c0[2];bv1[3]=c0[3];
                  bv1[4]=c1[0];bv1[5]=c1[1];bv1[6]=c1[2];bv1[7]=c1[3];
      o1 = MFMA16(pa, bv1, o1);
    }
#pragma unroll
    for (int r = 0; r < 4; ++r) {
      o_reg[rd][0][r] = o0[r] * rinv[r];
      o_reg[rd][1][r] = o1[r] * rinv[r];
    }
  }
  __syncthreads();

#pragma unroll
  for (int rd = 0; rd < 3; ++rd) {
    const int h = (wv >> 2) + 2 * rd;
#pragma unroll
    for (int r = 0; r < 4; ++r) {
      const int n = nt * 16 + lq * 4 + r;
      o_lds[n * 200 + h * 32 + lr]      = f2bf(o_reg[rd][0][r]);
      o_lds[n * 200 + h * 32 + 16 + lr] = f2bf(o_reg[rd][1][r]);
    }
  }
  __syncthreads();

  {
    const int mt = wv & 3;
    const int cc = wv >> 2;
    short8 af[6];
#pragma unroll
    for (int kb = 0; kb < 6; ++kb)
      af[kb] = *reinterpret_cast<const short8*>(&o_lds[(mt * 16 + lr) * 200 + kb * 32 + lq * 8]);
    float* op = out + (size_t)w * 9408;
    for (int ct = 0; ct < 6; ++ct) {
      const int cp = cc * 96 + ct * 16 + lr;
      short8 bf[6];
#pragma unroll
      for (int kb = 0; kb < 6; ++kb)
        bf[kb] = *reinterpret_cast<const short8*>(&wp_bf[cp * 192 + kb * 32 + lq * 8]);
      f32x4 acc = ZERO4;
#pragma unroll
      for (int kb = 0; kb < 6; ++kb) acc = MFMA16(af[kb], bf[kb], acc);
      const float bb = b_proj[cp];
      const int n0 = mt * 16 + lq * 4;
#pragma unroll
      for (int r = 0; r < 4; ++r)
        if (n0 + r < 49) op[(n0 + r) * 192 + cp] = acc[r] + bb;
    }
  }
}

extern "C" void kernel_launch(void* const* d_in, const int* in_sizes, int n_in,
                              void* d_out, int out_size, void* d_ws, size_t ws_size,
                              hipStream_t stream) {
  const float* x     = (const float*)d_in[0];
  const float* qg    = (const float*)d_in[1];
  const float* wqkv  = (const float*)d_in[2];
  const float* bqkv  = (const float*)d_in[3];
  const float* btab  = (const float*)d_in[4];
  const float* wproj = (const float*)d_in[5];
  const float* bproj = (const float*)d_in[6];
  float* out = (float*)d_out;

  char* ws = (char*)d_ws;
  unsigned short* wq_bf = (unsigned short*)(ws);            // 147456 B
  unsigned short* wp_bf = (unsigned short*)(ws + 147456);   //  73728 B
  unsigned short* q_bf  = (unsigned short*)(ws + 221184);   // 786432 B
  float* bias_t         = (float*)(ws + 1007616);           //  98304 B
  unsigned short* kv_g  = (unsigned short*)(ws + 1105920);  // 100663296 B -> total 101769216 B

  hipLaunchKernelGGL(prep_kernel, dim3(1536), dim3(256), 0, stream,
                     qg, wqkv, wproj, btab, wq_bf, wp_bf, q_bf, bias_t);
  if (ws_size >= 101769216ull) {
    hipLaunchKernelGGL(kv_proj, dim3(2048), dim3(512), 0, stream,
                       x, bqkv, wq_bf, kv_g);
    hipLaunchKernelGGL(attn_proj, dim3(2048), dim3(512), 0, stream,
                       bproj, wp_bf, q_bf, bias_t, kv_g, out);
  } else {
    hipLaunchKernelGGL(fused_win_attn, dim3(2048), dim3(512), 79360, stream,
                       x, bqkv, bproj, wq_bf, wp_bf, q_bf, bias_t, out);
  }
}

// Round 7
// 91.580 us; speedup vs baseline: 3.7117x; 2.1620x over previous
//
#include <hip/hip_runtime.h>
#include <hip/hip_bf16.h>

typedef __attribute__((ext_vector_type(8))) short short8;   // 8 bf16 = MFMA A/B frag
typedef __attribute__((ext_vector_type(4))) short short4v;  // 4 bf16
typedef __attribute__((ext_vector_type(4))) float f32x4;    // MFMA C/D

#define MFMA16(A,B,C) __builtin_amdgcn_mfma_f32_16x16x32_bf16((A),(B),(C),0,0,0)

static __device__ __forceinline__ unsigned short f2bf(float f) {
  unsigned int u = __float_as_uint(f);
  unsigned int rnd = 0x7fffu + ((u >> 16) & 1u);   // round-to-nearest-even
  return (unsigned short)((u + rnd) >> 16);
}

// ---------------- prep: tables in MFMA-fragment order ----------------
// wq_c  [wv][ct][kb][lane][8]  bf16 (147456)   B-frags for KV GEMM
// wp_c  [cc][ct][kb][lane][8]  bf16 (36864)    B-frags for out proj
// q_bf  [img][h][64][32]       bf16 (pre-scaled, padded)
// bias_c[h][nt][lane][mt*4+r]  f32  (24576)    bias in S^T C-layout order
__global__ void prep_kernel(const float* __restrict__ qg,
                            const float* __restrict__ wqkv,
                            const float* __restrict__ wproj,
                            const float* __restrict__ btab,
                            unsigned short* __restrict__ wq_c,
                            unsigned short* __restrict__ wp_c,
                            unsigned short* __restrict__ q_bf,
                            float* __restrict__ bias_c)
{
  const int t = blockIdx.x * 256 + threadIdx.x;
  if (t < 32*6*64*32) {                 // q: [img][h][n(64)][d(32)], *scale, zero-pad
    const int d = t & 31, n = (t >> 5) & 63;
    const int bh = t >> 11;
    const int h = bh % 6, b = bh / 6;
    float v = 0.f;
    if (n < 49) v = qg[((b * 6 + h) * 49 + n) * 32 + d] * 0.17677669529663687f;
    q_bf[t] = f2bf(v);
  }
  if (t < 8*3*6*64*8) {                 // wq_c: frag order
    const int e = t & 7, l = (t >> 3) & 63;
    const int kb = (t >> 9) % 6, g = (t >> 9) / 6;
    const int ct = g % 3, wv = g / 3;
    const int j = wv * 48 + ct * 16 + (l & 15);
    const int c = kb * 32 + (l >> 4) * 8 + e;
    wq_c[t] = f2bf(wqkv[j * 192 + c]);
  }
  if (t < 2*6*6*64*8) {                 // wp_c: frag order
    const int e = t & 7, l = (t >> 3) & 63;
    const int kb = (t >> 9) % 6, g = (t >> 9) / 6;
    const int ct = g % 6, cc = g / 6;
    const int cp = cc * 96 + ct * 16 + (l & 15);
    const int c = kb * 32 + (l >> 4) * 8 + e;
    wp_c[t] = f2bf(wproj[cp * 192 + c]);
  }
  if (t < 6*4*64*16) {                  // bias_c: [h][nt][l][mt*4+r]
    const int i4 = t & 15;              // mt*4 + r
    const int mt = i4 >> 2, r = i4 & 3;
    const int l = (t >> 4) & 63;
    const int nt = (t >> 10) & 3;
    const int h = t >> 12;
    const int m = mt * 16 + (l >> 4) * 4 + r;
    const int n = nt * 16 + (l & 15);
    float v;
    if (m >= 49) v = -1e30f;            // mask padded keys (exp -> 0)
    else if (n >= 49) v = 0.f;          // padded query rows: any finite value
    else {
      const int ci = n / 7, cj = n % 7, mi = m / 7, mj = m % 7;
      const int idx = (ci - mi + 6) * 13 + (cj - mj + 6);
      v = btab[idx * 6 + h];
    }
    bias_c[t] = v;
  }
}

// ---------------- fused window attention (R4 structure + frag-ordered tables) ----------------
// LDS: x_lds[64][200] @0 (aliased by p_lds) | k_lds[6][64][36] @12800 | vT_lds[6][32][68] @26624
//      o_lds[64][200] @12800 (aliases dead k/vT)   total 79360 B -> 2 blocks/CU
__global__ __launch_bounds__(512, 4)
void fused_win_attn(const float* __restrict__ x,
                    const float* __restrict__ b_qkv,
                    const float* __restrict__ b_proj,
                    const unsigned short* __restrict__ wq_c,
                    const unsigned short* __restrict__ wp_c,
                    const unsigned short* __restrict__ q_bf,
                    const float* __restrict__ bias_c,
                    float* __restrict__ out)
{
  extern __shared__ unsigned short lds[];
  unsigned short* x_lds  = lds;
  unsigned short* k_lds  = lds + 12800;
  unsigned short* vT_lds = lds + 26624;
  unsigned short* o_lds  = lds + 12800;

  const f32x4 ZERO4 = {0.f, 0.f, 0.f, 0.f};
  const int tid = threadIdx.x;
  const int wv = tid >> 6;
  const int l  = tid & 63;
  const int lr = l & 15;
  const int lq = l >> 4;
  const int w  = blockIdx.x;

  // ---- stage 1: x -> LDS bf16, zero-pad rows 49..63
  {
    const float* xw = x + (size_t)w * (49 * 192);
    for (int i = tid; i < 2352; i += 512) {
      const float4 v = *reinterpret_cast<const float4*>(xw + i * 4);
      const int e = i * 4;
      const int row = e / 192, col = e % 192;
      short4v pk;
      pk[0] = (short)f2bf(v.x); pk[1] = (short)f2bf(v.y);
      pk[2] = (short)f2bf(v.z); pk[3] = (short)f2bf(v.w);
      *reinterpret_cast<short4v*>(&x_lds[row * 200 + col]) = pk;
    }
    for (int i = tid; i < 720; i += 512) {
      const int e = i * 4;
      const int row = 49 + e / 192, col = e % 192;
      short4v z = {0, 0, 0, 0};
      *reinterpret_cast<short4v*>(&x_lds[row * 200 + col]) = z;
    }
  }
  __syncthreads();

  // ---- stage 2: kv = x @ w_qkv^T + b_qkv  -> k_lds, vT_lds (bf16)
  {
    short8 afr[4][6];
#pragma unroll
    for (int mt = 0; mt < 4; ++mt)
#pragma unroll
      for (int kb = 0; kb < 6; ++kb)
        afr[mt][kb] = *reinterpret_cast<const short8*>(
            &x_lds[(mt * 16 + lr) * 200 + kb * 32 + lq * 8]);

    for (int ct = 0; ct < 3; ++ct) {
      const int j = wv * 48 + ct * 16 + lr;   // 0..383
      short8 bfr[6];
#pragma unroll
      for (int kb = 0; kb < 6; ++kb)
        bfr[kb] = *reinterpret_cast<const short8*>(
            &wq_c[((((wv * 3) + ct) * 6 + kb) * 64 + l) * 8]);   // coalesced frag load
      const float bq = b_qkv[j];
      f32x4 acc[4];
#pragma unroll
      for (int mt = 0; mt < 4; ++mt) acc[mt] = ZERO4;
#pragma unroll
      for (int kb = 0; kb < 6; ++kb)
#pragma unroll
        for (int mt = 0; mt < 4; ++mt)
          acc[mt] = MFMA16(afr[mt][kb], bfr[kb], acc[mt]);

      if (j < 192) {                  // K: k_lds[h][n][36-pad]
        const int h = j >> 5, d = j & 31;
#pragma unroll
        for (int mt = 0; mt < 4; ++mt) {
          const int n0 = mt * 16 + lq * 4;
#pragma unroll
          for (int r = 0; r < 4; ++r)
            k_lds[h * 2304 + (n0 + r) * 36 + d] = f2bf(acc[mt][r] + bq);
        }
      } else {                        // V: vT_lds[h][d][68-pad]
        const int jj = j - 192, h = jj >> 5, d = jj & 31;
#pragma unroll
        for (int mt = 0; mt < 4; ++mt) {
          const int n0 = mt * 16 + lq * 4;
          short4v pk;
#pragma unroll
          for (int r = 0; r < 4; ++r) pk[r] = (short)f2bf(acc[mt][r] + bq);
          *reinterpret_cast<short4v*>(&vT_lds[h * 2176 + d * 68 + n0]) = pk;
        }
      }
    }
  }
  __syncthreads();

  // ---- stage 3: attention (swapped QK^T); O kept in registers until k/vT dead
  unsigned short* p_lds = x_lds + wv * (16 * 72);
  const int nt = wv & 3;
  const int img = w >> 6;
  f32x4 o_reg[3][2];
#pragma unroll
  for (int rd = 0; rd < 3; ++rd) {
    const int h = (wv >> 2) + 2 * rd;
    const short8 aq = *reinterpret_cast<const short8*>(
        &q_bf[((img * 6 + h) * 64 + nt * 16 + lr) * 32 + lq * 8]);
    f32x4 s[4];
#pragma unroll
    for (int mt = 0; mt < 4; ++mt) {
      const unsigned short* kp = &k_lds[h * 2304 + (mt * 16 + lr) * 36 + lq * 8];
      const short4v k0 = *reinterpret_cast<const short4v*>(kp);
      const short4v k1 = *reinterpret_cast<const short4v*>(kp + 4);
      short8 bk;
      bk[0]=k0[0]; bk[1]=k0[1]; bk[2]=k0[2]; bk[3]=k0[3];
      bk[4]=k1[0]; bk[5]=k1[1]; bk[6]=k1[2]; bk[7]=k1[3];
      s[mt] = MFMA16(bk, aq, ZERO4);          // D = S^T
    }
    // bias (coalesced frag-order float4) + exp in-lane; P^T packed b64 to LDS
    const float* bc = bias_c + ((h * 4 + nt) * 64 + l) * 16;
    float lsum = 0.f;
#pragma unroll
    for (int mt = 0; mt < 4; ++mt) {
      const float4 b4 = *reinterpret_cast<const float4*>(bc + mt * 4);
      const float p0 = __expf(s[mt][0] + b4.x);
      const float p1 = __expf(s[mt][1] + b4.y);
      const float p2 = __expf(s[mt][2] + b4.z);
      const float p3 = __expf(s[mt][3] + b4.w);
      lsum += (p0 + p1) + (p2 + p3);
      short4v pk;
      pk[0] = (short)f2bf(p0); pk[1] = (short)f2bf(p1);
      pk[2] = (short)f2bf(p2); pk[3] = (short)f2bf(p3);
      *reinterpret_cast<short4v*>(&p_lds[lr * 72 + mt * 16 + lq * 4]) = pk;
    }
    lsum += __shfl_xor(lsum, 16, 64);
    lsum += __shfl_xor(lsum, 32, 64);
    const float rs = 1.0f / lsum;
    float rinv[4];
#pragma unroll
    for (int r = 0; r < 4; ++r)
      rinv[r] = __shfl(rs, lq * 4 + r, 16);
    // PV
    f32x4 o0 = ZERO4, o1 = ZERO4;
#pragma unroll
    for (int kb = 0; kb < 2; ++kb) {
      const short8 pa = *reinterpret_cast<const short8*>(&p_lds[lr * 72 + kb * 32 + lq * 8]);
      const unsigned short* vp0 = &vT_lds[h * 2176 + lr * 68 + kb * 32 + lq * 8];
      const unsigned short* vp1 = &vT_lds[h * 2176 + (16 + lr) * 68 + kb * 32 + lq * 8];
      const short4v a0 = *reinterpret_cast<const short4v*>(vp0);
      const short4v a1 = *reinterpret_cast<const short4v*>(vp0 + 4);
      short8 bv0; bv0[0]=a0[0];bv0[1]=a0[1];bv0[2]=a0[2];bv0[3]=a0[3];
                  bv0[4]=a1[0];bv0[5]=a1[1];bv0[6]=a1[2];bv0[7]=a1[3];
      o0 = MFMA16(pa, bv0, o0);
      const short4v c0 = *reinterpret_cast<const short4v*>(vp1);
      const short4v c1 = *reinterpret_cast<const short4v*>(vp1 + 4);
      short8 bv1; bv1[0]=c0[0];bv1[1]=c0[1];bv1[2]=c0[2];bv1[3]=c0[3];
                  bv1[4]=c1[0];bv1[5]=c1[1];bv1[6]=c1[2];bv1[7]=c1[3];
      o1 = MFMA16(pa, bv1, o1);
    }
#pragma unroll
    for (int r = 0; r < 4; ++r) {
      o_reg[rd][0][r] = o0[r] * rinv[r];
      o_reg[rd][1][r] = o1[r] * rinv[r];
    }
  }
  __syncthreads();   // k/vT reads complete

  // ---- O registers -> o_lds (aliases dead k/vT)
#pragma unroll
  for (int rd = 0; rd < 3; ++rd) {
    const int h = (wv >> 2) + 2 * rd;
#pragma unroll
    for (int r = 0; r < 4; ++r) {
      const int n = nt * 16 + lq * 4 + r;
      o_lds[n * 200 + h * 32 + lr]      = f2bf(o_reg[rd][0][r]);
      o_lds[n * 200 + h * 32 + 16 + lr] = f2bf(o_reg[rd][1][r]);
    }
  }
  __syncthreads();

  // ---- stage 4: out = o @ w_proj^T + b_proj
  {
    const int mt = wv & 3;
    const int cc = wv >> 2;
    short8 af[6];
#pragma unroll
    for (int kb = 0; kb < 6; ++kb)
      af[kb] = *reinterpret_cast<const short8*>(&o_lds[(mt * 16 + lr) * 200 + kb * 32 + lq * 8]);
    float* op = out + (size_t)w * 9408;
    for (int ct = 0; ct < 6; ++ct) {
      const int cp = cc * 96 + ct * 16 + lr;
      short8 bf[6];
#pragma unroll
      for (int kb = 0; kb < 6; ++kb)
        bf[kb] = *reinterpret_cast<const short8*>(
            &wp_c[(((cc * 6 + ct) * 6 + kb) * 64 + l) * 8]);    // coalesced frag load
      f32x4 acc = ZERO4;
#pragma unroll
      for (int kb = 0; kb < 6; ++kb) acc = MFMA16(af[kb], bf[kb], acc);
      const float bb = b_proj[cp];
      const int n0 = mt * 16 + lq * 4;
#pragma unroll
      for (int r = 0; r < 4; ++r)
        if (n0 + r < 49) op[(n0 + r) * 192 + cp] = acc[r] + bb;
    }
  }
}

extern "C" void kernel_launch(void* const* d_in, const int* in_sizes, int n_in,
                              void* d_out, int out_size, void* d_ws, size_t ws_size,
                              hipStream_t stream) {
  const float* x     = (const float*)d_in[0];
  const float* qg    = (const float*)d_in[1];
  const float* wqkv  = (const float*)d_in[2];
  const float* bqkv  = (const float*)d_in[3];
  const float* btab  = (const float*)d_in[4];
  const float* wproj = (const float*)d_in[5];
  const float* bproj = (const float*)d_in[6];
  float* out = (float*)d_out;

  char* ws = (char*)d_ws;
  unsigned short* wq_c  = (unsigned short*)(ws);            // 147456 B
  unsigned short* wp_c  = (unsigned short*)(ws + 147456);   //  73728 B (uses 36864)
  unsigned short* q_bf  = (unsigned short*)(ws + 221184);   // 786432 B
  float* bias_c         = (float*)(ws + 1007616);           //  98304 B (uses 98304)

  hipLaunchKernelGGL(prep_kernel, dim3(1536), dim3(256), 0, stream,
                     qg, wqkv, wproj, btab, wq_c, wp_c, q_bf, bias_c);
  hipLaunchKernelGGL(fused_win_attn, dim3(2048), dim3(512), 79360, stream,
                     x, bqkv, bproj, wq_c, wp_c, q_bf, bias_c, out);
}